// Round 6
// baseline (334.426 us; speedup 1.0000x reference)
//
#include <hip/hip_runtime.h>
#include <hip/hip_bf16.h>

#define AS1 __attribute__((address_space(1)))
#define AS3 __attribute__((address_space(3)))

typedef unsigned short u16;
typedef short bf16x8 __attribute__((ext_vector_type(8)));
typedef unsigned short u16x8 __attribute__((ext_vector_type(8)));
typedef float f32x4 __attribute__((ext_vector_type(4)));

#define MFMA16 __builtin_amdgcn_mfma_f32_16x16x32_bf16

// ---------------- helpers ----------------

__device__ __forceinline__ u16 f2bf(float f) {        // RNE (finite data)
  union { float f; unsigned u; } c; c.f = f;
  unsigned u = c.u;
  u = u + 0x7fffu + ((u >> 16) & 1u);
  return (u16)(u >> 16);
}

__device__ __forceinline__ float fexp2(float x) {
#if __has_builtin(__builtin_amdgcn_exp2f)
  return __builtin_amdgcn_exp2f(x);
#else
  return exp2f(x);
#endif
}

// pack bf16(a) into low16, bf16(b) into high16 (truncating) — 1 v_perm_b32
__device__ __forceinline__ unsigned pack_bf(float a, float b) {
  union { float f; unsigned u; } ua, ub; ua.f = a; ub.f = b;
  return __builtin_amdgcn_perm(ub.u, ua.u, 0x07060302u);
}

__device__ __forceinline__ void gl_lds16(const void* g, void* l) {
  __builtin_amdgcn_global_load_lds((const AS1 void*)g, (AS3 void*)l, 16, 0, 0);
}

// ---------------- cast fp32 -> bf16, with 64-col-tile granule swizzle ----------------

__global__ void cast_all_kernel(const float* __restrict__ x,
                                const float* __restrict__ wqkv,
                                const float* __restrict__ wout,
                                u16* __restrict__ ws) {
  int i = blockIdx.x * blockDim.x + threadIdx.x;   // float4 index, 3145728 total
  const float4* src;
  int rel;
  size_t matbase;
  if (i < 2097152)      { src = (const float4*)x + i;                rel = i;           matbase = 0; }
  else if (i < 2883584) { src = (const float4*)wqkv + (i - 2097152); rel = i - 2097152; matbase = 8388608; }
  else                  { src = (const float4*)wout + (i - 2883584); rel = i - 2883584; matbase = 11534336; }
  float4 f = *src;
  ushort4 o;
  o.x = f2bf(f.x); o.y = f2bf(f.y); o.z = f2bf(f.z); o.w = f2bf(f.w);
  int fe  = rel * 4;
  int row = fe >> 10, c = fe & 1023;
  int newc = (c & ~63) | (((((c >> 3) ^ row) & 7) << 3)) | (c & 7);
  ((ushort4*)ws)[(matbase + (size_t)row * 1024 + newc) >> 2] = o;
}

// ---------------- GEMM: C[M,N] = A[M,K] * B[N,K]^T  (bf16 in, fp32 acc) ----------------

template<int EPI>
__global__ __launch_bounds__(256) void gemm_bt(
    const u16* __restrict__ A, const u16* __restrict__ Bm,
    float* __restrict__ Cf,
    u16* __restrict__ qd, u16* __restrict__ kd, u16* __restrict__ vd,
    int M, int N, int K)
{
  __shared__ u16 As[128 * 64];
  __shared__ u16 Bs[128 * 64];

  const int tid  = threadIdx.x;
  const int wave = tid >> 6, lane = tid & 63;
  const int quad = lane >> 4, l16 = lane & 15;
  const int bm = blockIdx.y * 128, bn = blockIdx.x * 128;
  const int wm = (wave >> 1) * 64, wn = (wave & 1) * 64;

  f32x4 acc[4][4] = {};

  const int srow = wave * 32 + (lane >> 3);
  const int scol = (lane & 7) * 8;

  for (int kt = 0; kt < K; kt += 64) {
    __syncthreads();
    #pragma unroll
    for (int i = 0; i < 4; ++i) {
      gl_lds16(&A[(size_t)(bm + srow + i * 8) * K + kt + scol], &As[(wave * 32 + i * 8) * 64]);
      gl_lds16(&Bm[(size_t)(bn + srow + i * 8) * K + kt + scol], &Bs[(wave * 32 + i * 8) * 64]);
    }
    __syncthreads();
    #pragma unroll
    for (int kk = 0; kk < 64; kk += 32) {
      bf16x8 af[4], bb[4];
      #pragma unroll
      for (int i = 0; i < 4; ++i) {
        int row = wm + i * 16 + l16;
        af[i] = *(const bf16x8*)&As[row * 64 + (((((kk >> 3) + quad) ^ row) & 7) << 3)];
      }
      #pragma unroll
      for (int j = 0; j < 4; ++j) {
        int row = wn + j * 16 + l16;
        bb[j] = *(const bf16x8*)&Bs[row * 64 + (((((kk >> 3) + quad) ^ row) & 7) << 3)];
      }
      #pragma unroll
      for (int i = 0; i < 4; ++i)
        #pragma unroll
        for (int j = 0; j < 4; ++j)
          acc[i][j] = MFMA16(af[i], bb[j], acc[i][j], 0, 0, 0);
    }
  }

  #pragma unroll
  for (int i = 0; i < 4; ++i) {
    #pragma unroll
    for (int j = 0; j < 4; ++j) {
      #pragma unroll
      for (int r = 0; r < 4; ++r) {
        int m = bm + wm + i * 16 + quad * 4 + r;
        int n = bn + wn + j * 16 + l16;
        float val = acc[i][j][r];
        if (EPI == 0) {
          Cf[(size_t)m * N + n] = val;
        } else {
          int part = n >> 10, rem = n & 1023;
          int h = rem >> 6, d = rem & 63;
          int b = m >> 12, s = m & 4095;
          if (part == 0) val *= 0.1803368801111244f;   // 0.125 * log2(e), exp2 path
          u16* dst = (part == 0) ? qd : (part == 1) ? kd : vd;
          dst[((size_t)((b * 16 + h) * 4096 + s)) * 64 + d] = f2bf(val);
        }
      }
    }
  }
}

// ---------------- V transpose: [B,H,S,64] -> [B,H,64,S] ----------------

__global__ __launch_bounds__(256) void transpose_v(const u16* __restrict__ vb,
                                                   u16* __restrict__ vt) {
  __shared__ u16 Lt[64 * 72];
  const int tid = threadIdx.x, bid = blockIdx.x;
  const int bh = bid & 31, st = (bid >> 5) << 6;
  const size_t base = (size_t)bh << 18;
  #pragma unroll
  for (int c = 0; c < 2; ++c) {
    int idx = tid * 8 + c * 2048;
    int row = idx >> 6, col = idx & 63;
    u16x8 vv = *(const u16x8*)&vb[base + (size_t)(st + row) * 64 + col];
    #pragma unroll
    for (int s = 0; s < 8; ++s) Lt[(col + s) * 72 + row] = vv[s];
  }
  __syncthreads();
  #pragma unroll
  for (int c = 0; c < 2; ++c) {
    int d = (tid >> 3) + c * 32;
    int sg = (tid & 7) * 8;
    u16x8 o;
    #pragma unroll
    for (int s = 0; s < 8; ++s) o[s] = Lt[d * 72 + sg + s];
    *(u16x8*)&vt[base + (size_t)d * 4096 + st + sg] = o;
  }
}

// ---------------- attention: 4 independent waves/block, prefetched K and V ----------------
// S^T = K·Q^T (A=K, B=Q): C regs = 4 consecutive keys of one query -> packed b64 P staging.
// Per tile: V prefetched at tile top (used ~600cyc later), K for next tile prefetched
// mid-tile into same regs (WAR resolved at issue). Incremental pointers, imm offsets.
// No barriers: each wave owns Ps[wave]. XCD locality: bh = bid&31.

__global__ __launch_bounds__(256, 3) void attn_kernel(
    const u16* __restrict__ qb, const u16* __restrict__ kb,
    const u16* __restrict__ vt, u16* __restrict__ ob)
{
  __shared__ u16 Ps[4][32 * 64];

  const int tid  = threadIdx.x;
  const int wave = tid >> 6;
  const int lane = tid & 63;
  const int quad = lane >> 4, l16 = lane & 15;
  const int bid  = blockIdx.x;
  const int bh   = bid & 31;
  const int t0   = (((bid >> 5) << 2) | wave) << 5;
  const size_t base = (size_t)bh << 18;
  u16* __restrict__ ps = &Ps[wave][0];

  const int l64 = l16 * 64 + quad * 8;   // A/B-operand lane offset into 64-wide rows

  // Q B-fragments (B[n=query l16][k=dh]); q pre-scaled by 0.125*log2e
  const u16* qp = qb + base + (size_t)t0 * 64 + l64;
  bf16x8 bq00 = *(const bf16x8*)(qp);
  bf16x8 bq01 = *(const bf16x8*)(qp + 32);
  bf16x8 bq10 = *(const bf16x8*)(qp + 1024);
  bf16x8 bq11 = *(const bf16x8*)(qp + 1056);

  const int lo = max(0, t0 - 511) >> 6;
  const int hi = (t0 + 31) >> 6;

  // K pointers at tile lo (advance +4096/tile); j=0,1 via kp0, j=2,3 via kp2
  const u16* kp0 = kb + base + (size_t)(lo << 6) * 64 + l64;
  const u16* kp2 = kp0 + 2048;
  // V^T pointers (row = jd*16+l16, advance +64/tile)
  const u16* vq  = vt + base + (size_t)l16 * 4096 + quad * 8;
  const u16* vp0 = vq + (lo << 6);
  const u16* vp1 = vp0 + 65536;
  const u16* vp2 = vp1 + 65536;
  const u16* vp3 = vp2 + 65536;

  // prefetch K fragments for first window tile
  bf16x8 kf[4][2];
  kf[0][0] = *(const bf16x8*)(kp0);        kf[0][1] = *(const bf16x8*)(kp0 + 32);
  kf[1][0] = *(const bf16x8*)(kp0 + 1024); kf[1][1] = *(const bf16x8*)(kp0 + 1056);
  kf[2][0] = *(const bf16x8*)(kp2);        kf[2][1] = *(const bf16x8*)(kp2 + 32);
  kf[3][0] = *(const bf16x8*)(kp2 + 1024); kf[3][1] = *(const bf16x8*)(kp2 + 1056);

  f32x4 oacc[2][4] = {};
  f32x4 lacc[2] = {};
  bf16x8 ones;
  #pragma unroll
  for (int s = 0; s < 8; ++s) ones[s] = (short)0x3F80;

  // ======== prefix tile (keys 0..15 causal; keys 16..31 zero-filled in Ps) ========
  {
    const u16* kpre = kb + base + l64;
    bf16x8 pk0 = *(const bf16x8*)(kpre);
    bf16x8 pk1 = *(const bf16x8*)(kpre + 32);
    bf16x8 pv[4];
    pv[0] = *(const bf16x8*)(vq);
    pv[1] = *(const bf16x8*)(vq + 65536);
    pv[2] = *(const bf16x8*)(vq + 131072);
    pv[3] = *(const bf16x8*)(vq + 196608);

    #pragma unroll
    for (int i = 0; i < 2; ++i) {
      f32x4 t4 = {};
      t4 = MFMA16(pk0, i ? bq10 : bq00, t4, 0, 0, 0);
      t4 = MFMA16(pk1, i ? bq11 : bq01, t4, 0, 0, 0);
      int row = i * 16 + l16;
      int qpos = t0 + row;
      float p[4];
      #pragma unroll
      for (int r = 0; r < 4; ++r) {
        int kpos = quad * 4 + r;
        p[r] = fexp2(kpos <= qpos ? t4[r] : -1e30f);
      }
      uint2 w;
      w.x = pack_bf(p[0], p[1]);
      w.y = pack_bf(p[2], p[3]);
      *(uint2*)&ps[row * 64 + ((quad ^ l16) & 15) * 4] = w;
      uint2 z; z.x = 0u; z.y = 0u;
      *(uint2*)&ps[row * 64 + (((4 + quad) ^ l16) & 15) * 4] = z;
    }
    #pragma unroll
    for (int i = 0; i < 2; ++i) {
      int row = i * 16 + l16;
      uint2 r0 = *(uint2*)&ps[row * 64 + (((2 * quad) ^ l16) & 15) * 4];
      uint2 r1 = *(uint2*)&ps[row * 64 + (((2 * quad + 1) ^ l16) & 15) * 4];
      union { uint4 u; bf16x8 v; } cc; cc.u = make_uint4(r0.x, r0.y, r1.x, r1.y);
      bf16x8 ap = cc.v;
      lacc[i] = MFMA16(ap, ones, lacc[i], 0, 0, 0);
      #pragma unroll
      for (int jd = 0; jd < 4; ++jd)
        oacc[i][jd] = MFMA16(ap, pv[jd], oacc[i][jd], 0, 0, 0);
    }
  }

  // ======== sliding-window tiles ========
  for (int t = lo; t <= hi; ++t) {
    const int kb0 = t << 6;
    const bool full = (kb0 >= 16) && (kb0 + 63 <= t0) && (kb0 >= t0 + 31 - 511);

    // ---- V prefetch for this tile (consumed at PV, far below) ----
    bf16x8 bv[2][4];
    bv[0][0] = *(const bf16x8*)(vp0);  bv[1][0] = *(const bf16x8*)(vp0 + 32);
    bv[0][1] = *(const bf16x8*)(vp1);  bv[1][1] = *(const bf16x8*)(vp1 + 32);
    bv[0][2] = *(const bf16x8*)(vp2);  bv[1][2] = *(const bf16x8*)(vp2 + 32);
    bv[0][3] = *(const bf16x8*)(vp3);  bv[1][3] = *(const bf16x8*)(vp3 + 32);

    // ---- S^T = K Q^T ----
    f32x4 sc[4][2];
    #pragma unroll
    for (int j = 0; j < 4; ++j) {
      #pragma unroll
      for (int i = 0; i < 2; ++i) {
        f32x4 t4 = {};
        t4 = MFMA16(kf[j][0], i ? bq10 : bq00, t4, 0, 0, 0);
        t4 = MFMA16(kf[j][1], i ? bq11 : bq01, t4, 0, 0, 0);
        sc[j][i] = t4;
      }
    }

    // ---- prefetch next tile's K (regs free after QK issue) ----
    if (t < hi) {
      kp0 += 4096; kp2 += 4096;
      kf[0][0] = *(const bf16x8*)(kp0);        kf[0][1] = *(const bf16x8*)(kp0 + 32);
      kf[1][0] = *(const bf16x8*)(kp0 + 1024); kf[1][1] = *(const bf16x8*)(kp0 + 1056);
      kf[2][0] = *(const bf16x8*)(kp2);        kf[2][1] = *(const bf16x8*)(kp2 + 32);
      kf[3][0] = *(const bf16x8*)(kp2 + 1024); kf[3][1] = *(const bf16x8*)(kp2 + 1056);
    }

    // ---- mask + exp + pack -> Ps ----
    #pragma unroll
    for (int j = 0; j < 4; ++j) {
      #pragma unroll
      for (int i = 0; i < 2; ++i) {
        int row = i * 16 + l16;
        float p[4];
        if (full) {
          #pragma unroll
          for (int r = 0; r < 4; ++r) p[r] = fexp2(sc[j][i][r]);
        } else {
          int qpos = t0 + row;
          #pragma unroll
          for (int r = 0; r < 4; ++r) {
            int kpos = kb0 + j * 16 + quad * 4 + r;
            int diff = qpos - kpos;
            bool ok = (diff >= 0) && (diff < 512) && (kpos >= 16);
            p[r] = fexp2(ok ? sc[j][i][r] : -1e30f);
          }
        }
        uint2 w;
        w.x = pack_bf(p[0], p[1]);
        w.y = pack_bf(p[2], p[3]);
        *(uint2*)&ps[row * 64 + (((j * 4 + quad) ^ l16) & 15) * 4] = w;
      }
    }

    // ---- P·V + l accumulation ----
    #pragma unroll
    for (int i = 0; i < 2; ++i) {
      int row = i * 16 + l16;
      #pragma unroll
      for (int h = 0; h < 2; ++h) {
        int g0 = h * 8 + 2 * quad;
        uint2 r0 = *(uint2*)&ps[row * 64 + ((g0 ^ l16) & 15) * 4];
        uint2 r1 = *(uint2*)&ps[row * 64 + (((g0 + 1) ^ l16) & 15) * 4];
        union { uint4 u; bf16x8 v; } cc; cc.u = make_uint4(r0.x, r0.y, r1.x, r1.y);
        bf16x8 ap = cc.v;
        lacc[i] = MFMA16(ap, ones, lacc[i], 0, 0, 0);
        #pragma unroll
        for (int jd = 0; jd < 4; ++jd)
          oacc[i][jd] = MFMA16(ap, bv[h][jd], oacc[i][jd], 0, 0, 0);
      }
    }

    vp0 += 64; vp1 += 64; vp2 += 64; vp3 += 64;
  }

  // ---- epilogue: O/l -> bf16 [B,S,H*64], granule-swizzled for GEMM3 staging ----
  const int b = bh >> 4, h = bh & 15;
  #pragma unroll
  for (int i = 0; i < 2; ++i) {
    #pragma unroll
    for (int r = 0; r < 4; ++r) {
      float inv = 1.f / lacc[i][r];
      int srow = t0 + i * 16 + quad * 4 + r;
      size_t rowoff = ((size_t)(b * 4096 + srow)) * 1024 + h * 64;
      #pragma unroll
      for (int jd = 0; jd < 4; ++jd) {
        int g = ((jd * 2 + (l16 >> 3)) ^ srow) & 7;
        ob[rowoff + (g << 3) + (l16 & 7)] = f2bf(oacc[i][jd][r] * inv);
      }
    }
  }
}

// ---------------- launch ----------------

extern "C" void kernel_launch(void* const* d_in, const int* in_sizes, int n_in,
                              void* d_out, int out_size, void* d_ws, size_t ws_size,
                              hipStream_t stream) {
  const float* x    = (const float*)d_in[0];
  const float* wqkv = (const float*)d_in[1];
  const float* wout = (const float*)d_in[2];
  float* out = (float*)d_out;

  u16* ws    = (u16*)d_ws;
  u16* xb    = ws;                                   // 8192*1024  (reused as obuf)
  u16* wqkvb = xb + (size_t)8192 * 1024;             // 3072*1024
  u16* woutb = wqkvb + (size_t)3072 * 1024;          // 1024*1024
  u16* qbuf  = woutb + (size_t)1024 * 1024;          // [2,16,4096,64]
  u16* kbuf  = qbuf + (size_t)8388608;
  u16* vbuf  = kbuf + (size_t)8388608;
  u16* vtb   = vbuf + (size_t)8388608;               // [2,16,64,4096]
  u16* obuf  = xb;                                   // alias: xb dead after gemm1

  cast_all_kernel<<<12288, 256, 0, stream>>>(x, wqkv, wout, ws);

  gemm_bt<1><<<dim3(24, 64), 256, 0, stream>>>(xb, wqkvb, nullptr, qbuf, kbuf, vbuf,
                                               8192, 3072, 1024);
  transpose_v<<<2048, 256, 0, stream>>>(vbuf, vtb);
  attn_kernel<<<1024, 256, 0, stream>>>(qbuf, kbuf, vtb, obuf);
  gemm_bt<0><<<dim3(8, 64), 256, 0, stream>>>(obuf, woutb, out, nullptr, nullptr, nullptr,
                                              8192, 1024, 1024);
}

// Round 7
// 261.901 us; speedup vs baseline: 1.2769x; 1.2769x over previous
//
#include <hip/hip_runtime.h>
#include <hip/hip_bf16.h>

#define AS1 __attribute__((address_space(1)))
#define AS3 __attribute__((address_space(3)))

typedef unsigned short u16;
typedef short bf16x8 __attribute__((ext_vector_type(8)));
typedef unsigned short u16x8 __attribute__((ext_vector_type(8)));
typedef float f32x4 __attribute__((ext_vector_type(4)));

#define MFMA16 __builtin_amdgcn_mfma_f32_16x16x32_bf16

// ---------------- helpers ----------------

__device__ __forceinline__ u16 f2bf(float f) {        // RNE (finite data)
  union { float f; unsigned u; } c; c.f = f;
  unsigned u = c.u;
  u = u + 0x7fffu + ((u >> 16) & 1u);
  return (u16)(u >> 16);
}

__device__ __forceinline__ float fexp2(float x) {
#if __has_builtin(__builtin_amdgcn_exp2f)
  return __builtin_amdgcn_exp2f(x);
#else
  return exp2f(x);
#endif
}

// pack bf16(a) low16, bf16(b) high16 (truncating) — 1 v_perm_b32
__device__ __forceinline__ unsigned pack_bf(float a, float b) {
  union { float f; unsigned u; } ua, ub; ua.f = a; ub.f = b;
  return __builtin_amdgcn_perm(ub.u, ua.u, 0x07060302u);
}

__device__ __forceinline__ void gl_lds16(const void* g, void* l) {
  __builtin_amdgcn_global_load_lds((const AS1 void*)g, (AS3 void*)l, 16, 0, 0);
}

// ---------------- cast fp32 -> bf16, with 64-col-tile granule swizzle ----------------

__global__ void cast_all_kernel(const float* __restrict__ x,
                                const float* __restrict__ wqkv,
                                const float* __restrict__ wout,
                                u16* __restrict__ ws) {
  int i = blockIdx.x * blockDim.x + threadIdx.x;   // float4 index, 3145728 total
  const float4* src;
  int rel;
  size_t matbase;
  if (i < 2097152)      { src = (const float4*)x + i;                rel = i;           matbase = 0; }
  else if (i < 2883584) { src = (const float4*)wqkv + (i - 2097152); rel = i - 2097152; matbase = 8388608; }
  else                  { src = (const float4*)wout + (i - 2883584); rel = i - 2883584; matbase = 11534336; }
  float4 f = *src;
  ushort4 o;
  o.x = f2bf(f.x); o.y = f2bf(f.y); o.z = f2bf(f.z); o.w = f2bf(f.w);
  int fe  = rel * 4;
  int row = fe >> 10, c = fe & 1023;
  int newc = (c & ~63) | (((((c >> 3) ^ row) & 7) << 3)) | (c & 7);
  ((ushort4*)ws)[(matbase + (size_t)row * 1024 + newc) >> 2] = o;
}

// ---------------- GEMM: C[M,N] = A[M,K] * B[N,K]^T  (bf16 in, fp32 acc) ----------------

template<int EPI>
__global__ __launch_bounds__(256) void gemm_bt(
    const u16* __restrict__ A, const u16* __restrict__ Bm,
    float* __restrict__ Cf,
    u16* __restrict__ qd, u16* __restrict__ kd, u16* __restrict__ vd,
    int M, int N, int K)
{
  __shared__ u16 As[128 * 64];
  __shared__ u16 Bs[128 * 64];

  const int tid  = threadIdx.x;
  const int wave = tid >> 6, lane = tid & 63;
  const int quad = lane >> 4, l16 = lane & 15;
  const int bm = blockIdx.y * 128, bn = blockIdx.x * 128;
  const int wm = (wave >> 1) * 64, wn = (wave & 1) * 64;

  f32x4 acc[4][4] = {};

  const int srow = wave * 32 + (lane >> 3);
  const int scol = (lane & 7) * 8;

  for (int kt = 0; kt < K; kt += 64) {
    __syncthreads();
    #pragma unroll
    for (int i = 0; i < 4; ++i) {
      gl_lds16(&A[(size_t)(bm + srow + i * 8) * K + kt + scol], &As[(wave * 32 + i * 8) * 64]);
      gl_lds16(&Bm[(size_t)(bn + srow + i * 8) * K + kt + scol], &Bs[(wave * 32 + i * 8) * 64]);
    }
    __syncthreads();
    #pragma unroll
    for (int kk = 0; kk < 64; kk += 32) {
      bf16x8 af[4], bb[4];
      #pragma unroll
      for (int i = 0; i < 4; ++i) {
        int row = wm + i * 16 + l16;
        af[i] = *(const bf16x8*)&As[row * 64 + (((((kk >> 3) + quad) ^ row) & 7) << 3)];
      }
      #pragma unroll
      for (int j = 0; j < 4; ++j) {
        int row = wn + j * 16 + l16;
        bb[j] = *(const bf16x8*)&Bs[row * 64 + (((((kk >> 3) + quad) ^ row) & 7) << 3)];
      }
      #pragma unroll
      for (int i = 0; i < 4; ++i)
        #pragma unroll
        for (int j = 0; j < 4; ++j)
          acc[i][j] = MFMA16(af[i], bb[j], acc[i][j], 0, 0, 0);
    }
  }

  #pragma unroll
  for (int i = 0; i < 4; ++i) {
    #pragma unroll
    for (int j = 0; j < 4; ++j) {
      #pragma unroll
      for (int r = 0; r < 4; ++r) {
        int m = bm + wm + i * 16 + quad * 4 + r;
        int n = bn + wn + j * 16 + l16;
        float val = acc[i][j][r];
        if (EPI == 0) {
          Cf[(size_t)m * N + n] = val;
        } else {
          int part = n >> 10, rem = n & 1023;
          int h = rem >> 6, d = rem & 63;
          int b = m >> 12, s = m & 4095;
          if (part == 0) val *= 0.1803368801111244f;   // 0.125 * log2(e), exp2 path
          u16* dst = (part == 0) ? qd : (part == 1) ? kd : vd;
          dst[((size_t)((b * 16 + h) * 4096 + s)) * 64 + d] = f2bf(val);
        }
      }
    }
  }
}

// ---------------- V transpose: [B,H,S,64] -> [B,H,64,S] ----------------

__global__ __launch_bounds__(256) void transpose_v(const u16* __restrict__ vb,
                                                   u16* __restrict__ vt) {
  __shared__ u16 Lt[64 * 72];
  const int tid = threadIdx.x, bid = blockIdx.x;
  const int bh = bid & 31, st = (bid >> 5) << 6;
  const size_t base = (size_t)bh << 18;
  #pragma unroll
  for (int c = 0; c < 2; ++c) {
    int idx = tid * 8 + c * 2048;
    int row = idx >> 6, col = idx & 63;
    u16x8 vv = *(const u16x8*)&vb[base + (size_t)(st + row) * 64 + col];
    #pragma unroll
    for (int s = 0; s < 8; ++s) Lt[(col + s) * 72 + row] = vv[s];
  }
  __syncthreads();
  #pragma unroll
  for (int c = 0; c < 2; ++c) {
    int d = (tid >> 3) + c * 32;
    int sg = (tid & 7) * 8;
    u16x8 o;
    #pragma unroll
    for (int s = 0; s < 8; ++s) o[s] = Lt[d * 72 + sg + s];
    *(u16x8*)&vt[base + (size_t)d * 4096 + st + sg] = o;
  }
}

// ---------------- attention: 4 independent waves/block, S^T trick, subtile fast paths ----
// S^T = K·Q^T (A=K, B=Q): C regs = 4 consecutive keys of one query -> packed b64 staging.
// Per 16x16 (j,i) subtile, wave-uniform 3-path: fully-masked -> write zeros (skip MFMA+exp);
// fully-valid -> exp-only; diagonal-crossing -> masked exp (1 sub + 1 ucmp + cndmask).
// K ping-pong double-buffered one tile ahead. No barriers; per-wave Ps slice.

__global__ __launch_bounds__(256) void attn_kernel(
    const u16* __restrict__ qb, const u16* __restrict__ kb,
    const u16* __restrict__ vt, u16* __restrict__ ob)
{
  __shared__ u16 Ps[4][32 * 64];

  const int tid  = threadIdx.x;
  const int wave = tid >> 6;
  const int lane = tid & 63;
  const int quad = lane >> 4, l16 = lane & 15;
  const int bid  = blockIdx.x;
  const int bh   = bid & 31;
  const int t0   = (((bid >> 5) << 2) | wave) << 5;
  const size_t base = (size_t)bh << 18;
  u16* __restrict__ ps = &Ps[wave][0];

  const int l64 = l16 * 64 + quad * 8;

  // Q B-fragments (B[n=query l16][k=dh]); q pre-scaled by 0.125*log2e
  const u16* qp = qb + base + (size_t)t0 * 64 + l64;
  bf16x8 bq00 = *(const bf16x8*)(qp);
  bf16x8 bq01 = *(const bf16x8*)(qp + 32);
  bf16x8 bq10 = *(const bf16x8*)(qp + 1024);
  bf16x8 bq11 = *(const bf16x8*)(qp + 1056);

  f32x4 oacc[2][4] = {};
  f32x4 lacc[2] = {};
  bf16x8 ones;
  #pragma unroll
  for (int s = 0; s < 8; ++s) ones[s] = (short)0x3F80;

  const int lo = max(0, t0 - 511) >> 6;
  const int hi = (t0 + 31) >> 6;

  auto loadK = [&](int kb0, bf16x8 (&kf)[4][2]) {
    #pragma unroll
    for (int j = 0; j < 4; ++j) {
      const u16* krow = kb + base + (size_t)(kb0 + j * 16) * 64 + l64;
      kf[j][0] = *(const bf16x8*)(krow);
      kf[j][1] = *(const bf16x8*)(krow + 32);
    }
  };

  bf16x8 ka[4][2], kb2[4][2];

  // ======== prefix tile (keys 0..15 causal; keys 16..31 zero-filled) ========
  {
    const u16* kpre = kb + base + l64;
    bf16x8 pk0 = *(const bf16x8*)(kpre);
    bf16x8 pk1 = *(const bf16x8*)(kpre + 32);
    loadK(lo << 6, ka);                        // prefetch first window tile

    #pragma unroll
    for (int i = 0; i < 2; ++i) {
      f32x4 t4 = {};
      t4 = MFMA16(pk0, i ? bq10 : bq00, t4, 0, 0, 0);
      t4 = MFMA16(pk1, i ? bq11 : bq01, t4, 0, 0, 0);
      int row = i * 16 + l16;
      int qpos = t0 + row;
      float p[4];
      #pragma unroll
      for (int r = 0; r < 4; ++r) {
        int kpos = quad * 4 + r;
        p[r] = (kpos <= qpos) ? fexp2(t4[r]) : 0.f;
      }
      uint2 w;
      w.x = pack_bf(p[0], p[1]);
      w.y = pack_bf(p[2], p[3]);
      *(uint2*)&ps[row * 64 + ((quad ^ l16) & 15) * 4] = w;
      uint2 z; z.x = 0u; z.y = 0u;
      *(uint2*)&ps[row * 64 + (((4 + quad) ^ l16) & 15) * 4] = z;
    }
    #pragma unroll
    for (int i = 0; i < 2; ++i) {
      int row = i * 16 + l16;
      uint2 r0 = *(uint2*)&ps[row * 64 + (((2 * quad) ^ l16) & 15) * 4];
      uint2 r1 = *(uint2*)&ps[row * 64 + (((2 * quad + 1) ^ l16) & 15) * 4];
      union { uint4 u; bf16x8 v; } cc; cc.u = make_uint4(r0.x, r0.y, r1.x, r1.y);
      bf16x8 ap = cc.v;
      lacc[i] = MFMA16(ap, ones, lacc[i], 0, 0, 0);
      #pragma unroll
      for (int jd = 0; jd < 4; ++jd) {
        bf16x8 bv = *(const bf16x8*)&vt[base + (size_t)(jd * 16 + l16) * 4096 + quad * 8];
        oacc[i][jd] = MFMA16(ap, bv, oacc[i][jd], 0, 0, 0);
      }
    }
  }

  // ======== sliding-window tiles ========
  auto tilec = [&](int kb0, bf16x8 (&kf)[4][2]) {
    #pragma unroll
    for (int j = 0; j < 4; ++j) {
      const int kmin = kb0 + j * 16;
      #pragma unroll
      for (int i = 0; i < 2; ++i) {
        const int qmin = t0 + i * 16;
        const int row  = i * 16 + l16;
        uint2* dst = (uint2*)&ps[row * 64 + (((j * 4 + quad) ^ l16) & 15) * 4];
        // wave-uniform subtile classification
        const bool sub_masked = (kmin > qmin + 15) || (qmin - kmin >= 527) || (kmin < 16);
        if (sub_masked) { uint2 z; z.x = 0u; z.y = 0u; *dst = z; continue; }
        f32x4 t4 = {};
        t4 = MFMA16(kf[j][0], i ? bq10 : bq00, t4, 0, 0, 0);
        t4 = MFMA16(kf[j][1], i ? bq11 : bq01, t4, 0, 0, 0);
        const bool sub_ok = (kmin + 15 <= qmin) && (qmin + 15 - kmin < 512);
        float p[4];
        if (sub_ok) {
          #pragma unroll
          for (int r = 0; r < 4; ++r) p[r] = fexp2(t4[r]);
        } else {
          int qpos = t0 + row;
          #pragma unroll
          for (int r = 0; r < 4; ++r) {
            int kpos = kmin + quad * 4 + r;       // kmin >= 16 guaranteed here
            unsigned diff = (unsigned)(qpos - kpos);
            p[r] = (diff < 512u) ? fexp2(t4[r]) : 0.f;
          }
        }
        uint2 w;
        w.x = pack_bf(p[0], p[1]);
        w.y = pack_bf(p[2], p[3]);
        *dst = w;
      }
    }
    // PV + l accumulation
    #pragma unroll
    for (int i = 0; i < 2; ++i) {
      int row = i * 16 + l16;
      #pragma unroll
      for (int h = 0; h < 2; ++h) {
        int g0 = h * 8 + 2 * quad;
        uint2 r0 = *(uint2*)&ps[row * 64 + ((g0 ^ l16) & 15) * 4];
        uint2 r1 = *(uint2*)&ps[row * 64 + (((g0 + 1) ^ l16) & 15) * 4];
        union { uint4 u; bf16x8 v; } cc; cc.u = make_uint4(r0.x, r0.y, r1.x, r1.y);
        bf16x8 ap = cc.v;
        lacc[i] = MFMA16(ap, ones, lacc[i], 0, 0, 0);
        #pragma unroll
        for (int jd = 0; jd < 4; ++jd) {
          bf16x8 bv = *(const bf16x8*)&vt[base + (size_t)(jd * 16 + l16) * 4096 + kb0 + h * 32 + quad * 8];
          oacc[i][jd] = MFMA16(ap, bv, oacc[i][jd], 0, 0, 0);
        }
      }
    }
  };

  for (int t = lo; t <= hi; t += 2) {
    if (t + 1 <= hi) loadK((t + 1) << 6, kb2);
    tilec(t << 6, ka);
    if (t + 1 <= hi) {
      if (t + 2 <= hi) loadK((t + 2) << 6, ka);
      tilec((t + 1) << 6, kb2);
    }
  }

  // ---- epilogue: O/l -> bf16 [B,S,H*64], granule-swizzled for GEMM3 staging ----
  const int b = bh >> 4, h = bh & 15;
  #pragma unroll
  for (int i = 0; i < 2; ++i) {
    #pragma unroll
    for (int r = 0; r < 4; ++r) {
      float inv = 1.f / lacc[i][r];
      int srow = t0 + i * 16 + quad * 4 + r;
      size_t rowoff = ((size_t)(b * 4096 + srow)) * 1024 + h * 64;
      #pragma unroll
      for (int jd = 0; jd < 4; ++jd) {
        int g = ((jd * 2 + (l16 >> 3)) ^ srow) & 7;
        ob[rowoff + (g << 3) + (l16 & 7)] = f2bf(oacc[i][jd][r] * inv);
      }
    }
  }
}

// ---------------- launch ----------------

extern "C" void kernel_launch(void* const* d_in, const int* in_sizes, int n_in,
                              void* d_out, int out_size, void* d_ws, size_t ws_size,
                              hipStream_t stream) {
  const float* x    = (const float*)d_in[0];
  const float* wqkv = (const float*)d_in[1];
  const float* wout = (const float*)d_in[2];
  float* out = (float*)d_out;

  u16* ws    = (u16*)d_ws;
  u16* xb    = ws;                                   // 8192*1024  (reused as obuf)
  u16* wqkvb = xb + (size_t)8192 * 1024;             // 3072*1024
  u16* woutb = wqkvb + (size_t)3072 * 1024;          // 1024*1024
  u16* qbuf  = woutb + (size_t)1024 * 1024;          // [2,16,4096,64]
  u16* kbuf  = qbuf + (size_t)8388608;
  u16* vbuf  = kbuf + (size_t)8388608;
  u16* vtb   = vbuf + (size_t)8388608;               // [2,16,64,4096]
  u16* obuf  = xb;                                   // alias: xb dead after gemm1

  cast_all_kernel<<<12288, 256, 0, stream>>>(x, wqkv, wout, ws);

  gemm_bt<1><<<dim3(24, 64), 256, 0, stream>>>(xb, wqkvb, nullptr, qbuf, kbuf, vbuf,
                                               8192, 3072, 1024);
  transpose_v<<<2048, 256, 0, stream>>>(vbuf, vtb);
  attn_kernel<<<1024, 256, 0, stream>>>(qbuf, kbuf, vtb, obuf);
  gemm_bt<0><<<dim3(8, 64), 256, 0, stream>>>(obuf, woutb, out, nullptr, nullptr, nullptr,
                                              8192, 1024, 1024);
}

// Round 8
// 242.578 us; speedup vs baseline: 1.3786x; 1.0797x over previous
//
#include <hip/hip_runtime.h>
#include <hip/hip_bf16.h>

#define AS1 __attribute__((address_space(1)))
#define AS3 __attribute__((address_space(3)))

typedef unsigned short u16;
typedef short bf16x8 __attribute__((ext_vector_type(8)));
typedef unsigned short u16x8 __attribute__((ext_vector_type(8)));
typedef float f32x4 __attribute__((ext_vector_type(4)));

#define MFMA16 __builtin_amdgcn_mfma_f32_16x16x32_bf16

// ---------------- helpers ----------------

__device__ __forceinline__ u16 f2bf(float f) {        // RNE (finite data)
  union { float f; unsigned u; } c; c.f = f;
  unsigned u = c.u;
  u = u + 0x7fffu + ((u >> 16) & 1u);
  return (u16)(u >> 16);
}

__device__ __forceinline__ float fexp2(float x) {
#if __has_builtin(__builtin_amdgcn_exp2f)
  return __builtin_amdgcn_exp2f(x);
#else
  return exp2f(x);
#endif
}

// pack bf16(a) low16, bf16(b) high16 (truncating) — 1 v_perm_b32
__device__ __forceinline__ unsigned pack_bf(float a, float b) {
  union { float f; unsigned u; } ua, ub; ua.f = a; ub.f = b;
  return __builtin_amdgcn_perm(ub.u, ua.u, 0x07060302u);
}

__device__ __forceinline__ void gl_lds16(const void* g, void* l) {
  __builtin_amdgcn_global_load_lds((const AS1 void*)g, (AS3 void*)l, 16, 0, 0);
}

// ---------------- cast fp32 -> bf16, with 64-col-tile granule swizzle ----------------

__global__ void cast_all_kernel(const float* __restrict__ x,
                                const float* __restrict__ wqkv,
                                const float* __restrict__ wout,
                                u16* __restrict__ ws) {
  int i = blockIdx.x * blockDim.x + threadIdx.x;   // float4 index, 3145728 total
  const float4* src;
  int rel;
  size_t matbase;
  if (i < 2097152)      { src = (const float4*)x + i;                rel = i;           matbase = 0; }
  else if (i < 2883584) { src = (const float4*)wqkv + (i - 2097152); rel = i - 2097152; matbase = 8388608; }
  else                  { src = (const float4*)wout + (i - 2883584); rel = i - 2883584; matbase = 11534336; }
  float4 f = *src;
  ushort4 o;
  o.x = f2bf(f.x); o.y = f2bf(f.y); o.z = f2bf(f.z); o.w = f2bf(f.w);
  int fe  = rel * 4;
  int row = fe >> 10, c = fe & 1023;
  int newc = (c & ~63) | (((((c >> 3) ^ row) & 7) << 3)) | (c & 7);
  ((ushort4*)ws)[(matbase + (size_t)row * 1024 + newc) >> 2] = o;
}

// ---------------- GEMM: C[M,N] = A[M,K] * B[N,K]^T  (bf16 in, fp32 acc) ----------------

template<int EPI>
__global__ __launch_bounds__(256) void gemm_bt(
    const u16* __restrict__ A, const u16* __restrict__ Bm,
    float* __restrict__ Cf,
    u16* __restrict__ qd, u16* __restrict__ kd, u16* __restrict__ vd,
    int M, int N, int K)
{
  __shared__ u16 As[128 * 64];
  __shared__ u16 Bs[128 * 64];

  const int tid  = threadIdx.x;
  const int wave = tid >> 6, lane = tid & 63;
  const int quad = lane >> 4, l16 = lane & 15;
  const int bm = blockIdx.y * 128, bn = blockIdx.x * 128;
  const int wm = (wave >> 1) * 64, wn = (wave & 1) * 64;

  f32x4 acc[4][4] = {};

  const int srow = wave * 32 + (lane >> 3);
  const int scol = (lane & 7) * 8;

  for (int kt = 0; kt < K; kt += 64) {
    __syncthreads();
    #pragma unroll
    for (int i = 0; i < 4; ++i) {
      gl_lds16(&A[(size_t)(bm + srow + i * 8) * K + kt + scol], &As[(wave * 32 + i * 8) * 64]);
      gl_lds16(&Bm[(size_t)(bn + srow + i * 8) * K + kt + scol], &Bs[(wave * 32 + i * 8) * 64]);
    }
    __syncthreads();
    #pragma unroll
    for (int kk = 0; kk < 64; kk += 32) {
      bf16x8 af[4], bb[4];
      #pragma unroll
      for (int i = 0; i < 4; ++i) {
        int row = wm + i * 16 + l16;
        af[i] = *(const bf16x8*)&As[row * 64 + (((((kk >> 3) + quad) ^ row) & 7) << 3)];
      }
      #pragma unroll
      for (int j = 0; j < 4; ++j) {
        int row = wn + j * 16 + l16;
        bb[j] = *(const bf16x8*)&Bs[row * 64 + (((((kk >> 3) + quad) ^ row) & 7) << 3)];
      }
      #pragma unroll
      for (int i = 0; i < 4; ++i)
        #pragma unroll
        for (int j = 0; j < 4; ++j)
          acc[i][j] = MFMA16(af[i], bb[j], acc[i][j], 0, 0, 0);
    }
  }

  #pragma unroll
  for (int i = 0; i < 4; ++i) {
    #pragma unroll
    for (int j = 0; j < 4; ++j) {
      #pragma unroll
      for (int r = 0; r < 4; ++r) {
        int m = bm + wm + i * 16 + quad * 4 + r;
        int n = bn + wn + j * 16 + l16;
        float val = acc[i][j][r];
        if (EPI == 0) {
          Cf[(size_t)m * N + n] = val;
        } else {
          int part = n >> 10, rem = n & 1023;
          int h = rem >> 6, d = rem & 63;
          int b = m >> 12, s = m & 4095;
          if (part == 0) val *= 0.1803368801111244f;   // 0.125 * log2(e), exp2 path
          u16* dst = (part == 0) ? qd : (part == 1) ? kd : vd;
          dst[((size_t)((b * 16 + h) * 4096 + s)) * 64 + d] = f2bf(val);
        }
      }
    }
  }
}

// ---------------- V pack: [B,H,S,64] -> operand-order [B,H, tile(64), jd(4), h(2), lane(64), 8] ----
// Attn V-frag load (jd,h) becomes 64 lanes x 16B = one contiguous 1KB block (single TA op).
// value at off = jd*1024 + h*512 + lane*8 + s  is  V[key = h*32 + (lane>>4)*8 + s][dh = jd*16 + (lane&15)]

__global__ __launch_bounds__(256) void pack_v(const u16* __restrict__ vb,
                                              u16* __restrict__ vt) {
  __shared__ u16 Lt[64 * 72];
  const int tid = threadIdx.x, bid = blockIdx.x;
  const int bh = bid & 31, t = bid >> 5;
  const size_t base = (size_t)bh << 18;
  #pragma unroll
  for (int c = 0; c < 2; ++c) {
    int idx = tid * 8 + c * 2048;
    int row = idx >> 6, col = idx & 63;                 // row=key, col=dh
    u16x8 vv = *(const u16x8*)&vb[base + (size_t)(t * 64 + row) * 64 + col];
    #pragma unroll
    for (int s = 0; s < 8; ++s) Lt[(col + s) * 72 + row] = vv[s];
  }
  __syncthreads();
  #pragma unroll
  for (int c = 0; c < 2; ++c) {
    int w = tid + c * 256;                              // 512 chunks
    int dh = w >> 3, k8 = w & 7;
    u16x8 o;
    #pragma unroll
    for (int s = 0; s < 8; ++s) o[s] = Lt[dh * 72 + k8 * 8 + s];
    int off = ((dh >> 4) << 10) | ((k8 >> 2) << 9) | ((k8 & 3) << 7) | ((dh & 15) << 3);
    *(u16x8*)&vt[base + (size_t)t * 4096 + off] = o;
  }
}

// ---------------- attention: 4 independent waves/block, S^T trick, coalesced V ----------------
// S^T = K·Q^T (A=K, B=Q): C regs = 4 consecutive keys of one query -> packed b64 staging.
// Per 16x16 (j,i) subtile, wave-uniform 3-path (masked/full/diagonal). K ping-pong one tile
// ahead. V frags from operand-order vt: one 1KB contiguous load each, reused across i.

__global__ __launch_bounds__(256) void attn_kernel(
    const u16* __restrict__ qb, const u16* __restrict__ kb,
    const u16* __restrict__ vt, u16* __restrict__ ob)
{
  __shared__ u16 Ps[4][32 * 64];

  const int tid  = threadIdx.x;
  const int wave = tid >> 6;
  const int lane = tid & 63;
  const int quad = lane >> 4, l16 = lane & 15;
  const int bid  = blockIdx.x;
  const int bh   = bid & 31;
  const int t0   = (((bid >> 5) << 2) | wave) << 5;
  const size_t base = (size_t)bh << 18;
  u16* __restrict__ ps = &Ps[wave][0];

  const int l64 = l16 * 64 + quad * 8;
  const u16* vbase = vt + base + lane * 8;   // + tile*4096 + jd*1024 + h*512

  // Q B-fragments (B[n=query l16][k=dh]); q pre-scaled by 0.125*log2e
  const u16* qp = qb + base + (size_t)t0 * 64 + l64;
  bf16x8 bq00 = *(const bf16x8*)(qp);
  bf16x8 bq01 = *(const bf16x8*)(qp + 32);
  bf16x8 bq10 = *(const bf16x8*)(qp + 1024);
  bf16x8 bq11 = *(const bf16x8*)(qp + 1056);

  f32x4 oacc[2][4] = {};
  f32x4 lacc[2] = {};
  bf16x8 ones;
  #pragma unroll
  for (int s = 0; s < 8; ++s) ones[s] = (short)0x3F80;

  const int lo = max(0, t0 - 511) >> 6;
  const int hi = (t0 + 31) >> 6;

  auto loadK = [&](int kb0, bf16x8 (&kf)[4][2]) {
    #pragma unroll
    for (int j = 0; j < 4; ++j) {
      const u16* krow = kb + base + (size_t)(kb0 + j * 16) * 64 + l64;
      kf[j][0] = *(const bf16x8*)(krow);
      kf[j][1] = *(const bf16x8*)(krow + 32);
    }
  };

  bf16x8 ka[4][2], kb2[4][2];

  // ======== prefix tile (keys 0..15 causal; keys 16..31 zero-filled) ========
  {
    const u16* kpre = kb + base + l64;
    bf16x8 pk0 = *(const bf16x8*)(kpre);
    bf16x8 pk1 = *(const bf16x8*)(kpre + 32);
    loadK(lo << 6, ka);                        // prefetch first window tile
    bf16x8 pv[4];
    #pragma unroll
    for (int jd = 0; jd < 4; ++jd)
      pv[jd] = *(const bf16x8*)(vbase + jd * 1024);   // tile 0, h=0

    #pragma unroll
    for (int i = 0; i < 2; ++i) {
      f32x4 t4 = {};
      t4 = MFMA16(pk0, i ? bq10 : bq00, t4, 0, 0, 0);
      t4 = MFMA16(pk1, i ? bq11 : bq01, t4, 0, 0, 0);
      int row = i * 16 + l16;
      int qpos = t0 + row;
      float p[4];
      #pragma unroll
      for (int r = 0; r < 4; ++r) {
        int kpos = quad * 4 + r;
        p[r] = (kpos <= qpos) ? fexp2(t4[r]) : 0.f;
      }
      uint2 w;
      w.x = pack_bf(p[0], p[1]);
      w.y = pack_bf(p[2], p[3]);
      *(uint2*)&ps[row * 64 + ((quad ^ l16) & 15) * 4] = w;
      uint2 z; z.x = 0u; z.y = 0u;
      *(uint2*)&ps[row * 64 + (((4 + quad) ^ l16) & 15) * 4] = z;
    }
    #pragma unroll
    for (int i = 0; i < 2; ++i) {
      int row = i * 16 + l16;
      uint2 r0 = *(uint2*)&ps[row * 64 + (((2 * quad) ^ l16) & 15) * 4];
      uint2 r1 = *(uint2*)&ps[row * 64 + (((2 * quad + 1) ^ l16) & 15) * 4];
      union { uint4 u; bf16x8 v; } cc; cc.u = make_uint4(r0.x, r0.y, r1.x, r1.y);
      bf16x8 ap = cc.v;
      lacc[i] = MFMA16(ap, ones, lacc[i], 0, 0, 0);
      #pragma unroll
      for (int jd = 0; jd < 4; ++jd)
        oacc[i][jd] = MFMA16(ap, pv[jd], oacc[i][jd], 0, 0, 0);
    }
  }

  // ======== sliding-window tiles ========
  auto tilec = [&](int kb0, bf16x8 (&kf)[4][2]) {
    #pragma unroll
    for (int j = 0; j < 4; ++j) {
      const int kmin = kb0 + j * 16;
      #pragma unroll
      for (int i = 0; i < 2; ++i) {
        const int qmin = t0 + i * 16;
        const int row  = i * 16 + l16;
        uint2* dst = (uint2*)&ps[row * 64 + (((j * 4 + quad) ^ l16) & 15) * 4];
        // wave-uniform subtile classification
        const bool sub_masked = (kmin > qmin + 15) || (qmin - kmin >= 527) || (kmin < 16);
        if (sub_masked) { uint2 z; z.x = 0u; z.y = 0u; *dst = z; continue; }
        f32x4 t4 = {};
        t4 = MFMA16(kf[j][0], i ? bq10 : bq00, t4, 0, 0, 0);
        t4 = MFMA16(kf[j][1], i ? bq11 : bq01, t4, 0, 0, 0);
        const bool sub_ok = (kmin + 15 <= qmin) && (qmin + 15 - kmin < 512);
        float p[4];
        if (sub_ok) {
          #pragma unroll
          for (int r = 0; r < 4; ++r) p[r] = fexp2(t4[r]);
        } else {
          int qpos = t0 + row;
          #pragma unroll
          for (int r = 0; r < 4; ++r) {
            int kpos = kmin + quad * 4 + r;       // kmin >= 16 guaranteed here
            unsigned diff = (unsigned)(qpos - kpos);
            p[r] = (diff < 512u) ? fexp2(t4[r]) : 0.f;
          }
        }
        uint2 w;
        w.x = pack_bf(p[0], p[1]);
        w.y = pack_bf(p[2], p[3]);
        *dst = w;
      }
    }
    // PV + l accumulation; V frags contiguous 1KB each, reused across i
    const u16* vp = vbase + (size_t)kb0 * 64;
    #pragma unroll
    for (int h = 0; h < 2; ++h) {
      bf16x8 bv0 = *(const bf16x8*)(vp + h * 512);
      bf16x8 bv1 = *(const bf16x8*)(vp + 1024 + h * 512);
      bf16x8 bv2 = *(const bf16x8*)(vp + 2048 + h * 512);
      bf16x8 bv3 = *(const bf16x8*)(vp + 3072 + h * 512);
      #pragma unroll
      for (int i = 0; i < 2; ++i) {
        int row = i * 16 + l16;
        int g0 = h * 8 + 2 * quad;
        uint2 r0 = *(uint2*)&ps[row * 64 + ((g0 ^ l16) & 15) * 4];
        uint2 r1 = *(uint2*)&ps[row * 64 + (((g0 + 1) ^ l16) & 15) * 4];
        union { uint4 u; bf16x8 v; } cc; cc.u = make_uint4(r0.x, r0.y, r1.x, r1.y);
        bf16x8 ap = cc.v;
        lacc[i] = MFMA16(ap, ones, lacc[i], 0, 0, 0);
        oacc[i][0] = MFMA16(ap, bv0, oacc[i][0], 0, 0, 0);
        oacc[i][1] = MFMA16(ap, bv1, oacc[i][1], 0, 0, 0);
        oacc[i][2] = MFMA16(ap, bv2, oacc[i][2], 0, 0, 0);
        oacc[i][3] = MFMA16(ap, bv3, oacc[i][3], 0, 0, 0);
      }
    }
  };

  for (int t = lo; t <= hi; t += 2) {
    if (t + 1 <= hi) loadK((t + 1) << 6, kb2);
    tilec(t << 6, ka);
    if (t + 1 <= hi) {
      if (t + 2 <= hi) loadK((t + 2) << 6, ka);
      tilec((t + 1) << 6, kb2);
    }
  }

  // ---- epilogue: O/l -> bf16 [B,S,H*64], granule-swizzled for GEMM3 staging ----
  const int b = bh >> 4, h = bh & 15;
  #pragma unroll
  for (int i = 0; i < 2; ++i) {
    #pragma unroll
    for (int r = 0; r < 4; ++r) {
      float inv = 1.f / lacc[i][r];
      int srow = t0 + i * 16 + quad * 4 + r;
      size_t rowoff = ((size_t)(b * 4096 + srow)) * 1024 + h * 64;
      #pragma unroll
      for (int jd = 0; jd < 4; ++jd) {
        int g = ((jd * 2 + (l16 >> 3)) ^ srow) & 7;
        ob[rowoff + (g << 3) + (l16 & 7)] = f2bf(oacc[i][jd][r] * inv);
      }
    }
  }
}

// ---------------- launch ----------------

extern "C" void kernel_launch(void* const* d_in, const int* in_sizes, int n_in,
                              void* d_out, int out_size, void* d_ws, size_t ws_size,
                              hipStream_t stream) {
  const float* x    = (const float*)d_in[0];
  const float* wqkv = (const float*)d_in[1];
  const float* wout = (const float*)d_in[2];
  float* out = (float*)d_out;

  u16* ws    = (u16*)d_ws;
  u16* xb    = ws;                                   // 8192*1024  (reused as obuf)
  u16* wqkvb = xb + (size_t)8192 * 1024;             // 3072*1024
  u16* woutb = wqkvb + (size_t)3072 * 1024;          // 1024*1024
  u16* qbuf  = woutb + (size_t)1024 * 1024;          // [2,16,4096,64]
  u16* kbuf  = qbuf + (size_t)8388608;
  u16* vbuf  = kbuf + (size_t)8388608;
  u16* vtb   = vbuf + (size_t)8388608;               // operand-order V
  u16* obuf  = xb;                                   // alias: xb dead after gemm1

  cast_all_kernel<<<12288, 256, 0, stream>>>(x, wqkv, wout, ws);

  gemm_bt<1><<<dim3(24, 64), 256, 0, stream>>>(xb, wqkvb, nullptr, qbuf, kbuf, vbuf,
                                               8192, 3072, 1024);
  pack_v<<<2048, 256, 0, stream>>>(vbuf, vtb);
  attn_kernel<<<1024, 256, 0, stream>>>(qbuf, kbuf, vtb, obuf);
  gemm_bt<0><<<dim3(8, 64), 256, 0, stream>>>(obuf, woutb, out, nullptr, nullptr, nullptr,
                                              8192, 1024, 1024);
}